// Round 1
// baseline (553.195 us; speedup 1.0000x reference)
//
#include <hip/hip_runtime.h>

typedef unsigned short u16;
typedef __bf16 bf16x8 __attribute__((ext_vector_type(8)));
typedef float floatx4 __attribute__((ext_vector_type(4)));

__device__ __forceinline__ u16 f2bf(float f) {
    unsigned int u = __float_as_uint(f);
    u = (u + 0x7FFFu + ((u >> 16) & 1u)) >> 16;
    return (u16)u;
}

// ---------------------------------------------------------------------------
// Transpose + fp32->bf16 convert: src is K x M (row-major), dst is M x K.
// ---------------------------------------------------------------------------
__global__ __launch_bounds__(256) void transpose_cvt(
    const float* __restrict__ src, u16* __restrict__ dst, int K, int M)
{
    __shared__ float t[32][33];
    const int bm = blockIdx.x * 32, bk = blockIdx.y * 32;
    const int tx = threadIdx.x, ty = threadIdx.y;
    #pragma unroll
    for (int i = ty; i < 32; i += 8)
        t[i][tx] = src[(long)(bk + i) * M + bm + tx];
    __syncthreads();
    #pragma unroll
    for (int i = ty; i < 32; i += 8)
        dst[(long)(bm + i) * K + bk + tx] = f2bf(t[tx][i]);
}

// ---------------------------------------------------------------------------
// LayerNorm over rows of 1024 fp32 -> bf16 out. One block (256 thr) per row.
// ---------------------------------------------------------------------------
__global__ __launch_bounds__(256) void ln_kernel(
    const float* __restrict__ x, const float* __restrict__ g,
    const float* __restrict__ bta, u16* __restrict__ out)
{
    const int row = blockIdx.x;
    const int tid = threadIdx.x;
    const float4 v = ((const float4*)(x + (long)row * 1024))[tid];
    float s  = v.x + v.y + v.z + v.w;
    float s2 = v.x*v.x + v.y*v.y + v.z*v.z + v.w*v.w;
    #pragma unroll
    for (int off = 1; off < 64; off <<= 1) {
        s  += __shfl_xor(s, off);
        s2 += __shfl_xor(s2, off);
    }
    __shared__ float red[8];
    const int wave = tid >> 6, lane = tid & 63;
    if (lane == 0) { red[wave] = s; red[4 + wave] = s2; }
    __syncthreads();
    s  = red[0] + red[1] + red[2] + red[3];
    s2 = red[4] + red[5] + red[6] + red[7];
    const float mu   = s * (1.0f / 1024.0f);
    const float var  = s2 * (1.0f / 1024.0f) - mu * mu;
    const float rstd = rsqrtf(var + 1e-5f);
    const int c = tid << 2;
    ushort4 o;
    o.x = f2bf((v.x - mu) * rstd * g[c + 0] + bta[c + 0]);
    o.y = f2bf((v.y - mu) * rstd * g[c + 1] + bta[c + 1]);
    o.z = f2bf((v.z - mu) * rstd * g[c + 2] + bta[c + 2]);
    o.w = f2bf((v.w - mu) * rstd * g[c + 3] + bta[c + 3]);
    ((ushort4*)(out + (long)row * 1024))[tid] = o;
}

// ---------------------------------------------------------------------------
// GEMM: C(N x M) = A(N x K, bf16 row-major) * Bt(M x K, bf16 row-major)^T
// 128x128 tile, BK=32, 256 threads (4 waves, 2x2), 4x4 16x16x32 MFMA per wave.
// MODE 0: out bf16, scatter to (B,H,S,hd) head layout, +bias     (QKV proj)
// MODE 1: out fp32 row-major, +bias +res                         (O-proj, FF2)
// MODE 2: out bf16 row-major, gelu(v+bias)                       (FF1)
// ---------------------------------------------------------------------------
template<int MODE>
__global__ __launch_bounds__(256) void gemm_kernel(
    const u16* __restrict__ A, const u16* __restrict__ Bt,
    const float* __restrict__ bias, const float* __restrict__ res,
    void* __restrict__ outv, int K, int M)
{
    __shared__ u16 As[128][40];   // pad 32 -> 40: 2-way bank aliasing only
    __shared__ u16 Bs[128][40];
    const int tid  = threadIdx.x;
    const int lane = tid & 63, wave = tid >> 6;
    const int wm = (wave >> 1) << 6, wn = (wave & 1) << 6;
    const int lrow = lane & 15, quad = lane >> 4, kq = quad << 3;
    const long rowbase = (long)blockIdx.y * 128;
    const long colbase = (long)blockIdx.x * 128;

    floatx4 acc[4][4];
    #pragma unroll
    for (int i = 0; i < 4; ++i)
        #pragma unroll
        for (int j = 0; j < 4; ++j)
            acc[i][j] = floatx4{0.f, 0.f, 0.f, 0.f};

    const int nK = K >> 5;
    for (int kt = 0; kt < nK; ++kt) {
        const int k0 = kt << 5;
        __syncthreads();
        #pragma unroll
        for (int it = 0; it < 2; ++it) {
            const int l = tid + it * 256;       // 512 16B loads per tile pair
            const int r = l >> 2, sg = (l & 3) << 3;
            *(uint4*)&As[r][sg] = *(const uint4*)(A  + (rowbase + r) * K + k0 + sg);
            *(uint4*)&Bs[r][sg] = *(const uint4*)(Bt + (colbase + r) * K + k0 + sg);
        }
        __syncthreads();
        bf16x8 af[4], bf[4];
        #pragma unroll
        for (int ms = 0; ms < 4; ++ms)
            af[ms] = *(const bf16x8*)&As[wm + (ms << 4) + lrow][kq];
        #pragma unroll
        for (int ns = 0; ns < 4; ++ns)
            bf[ns] = *(const bf16x8*)&Bs[wn + (ns << 4) + lrow][kq];
        #pragma unroll
        for (int ms = 0; ms < 4; ++ms)
            #pragma unroll
            for (int ns = 0; ns < 4; ++ns)
                acc[ms][ns] = __builtin_amdgcn_mfma_f32_16x16x32_bf16(
                    af[ms], bf[ns], acc[ms][ns], 0, 0, 0);
    }

    #pragma unroll
    for (int ms = 0; ms < 4; ++ms) {
        #pragma unroll
        for (int ns = 0; ns < 4; ++ns) {
            #pragma unroll
            for (int r = 0; r < 4; ++r) {
                const long row = rowbase + wm + (ms << 4) + (quad << 2) + r;
                const long col = colbase + wn + (ns << 4) + lrow;
                float v = acc[ms][ns][r] + bias[col];
                if constexpr (MODE == 0) {
                    const long b = row >> 11, s = row & 2047;
                    const long h = col >> 6,  d = col & 63;
                    ((u16*)outv)[(((b << 4) + h) * 2048 + s) * 64 + d] = f2bf(v);
                } else if constexpr (MODE == 1) {
                    const long idx = row * M + col;
                    ((float*)outv)[idx] = v + res[idx];
                } else {
                    const float gl = 0.5f * v * (1.0f + erff(v * 0.70710678118f));
                    ((u16*)outv)[row * M + col] = f2bf(gl);
                }
            }
        }
    }
}

// ---------------------------------------------------------------------------
// Flash attention: Q,K,V in (B*H, S, 64) bf16. One block = 64 queries of one
// (b,h); 4 waves x 16 queries. KV tiles of 64. Online softmax, P via LDS
// (C-layout -> A-layout transform), V staged transposed. Out: token-major
// (B*S, 1024) bf16.
// ---------------------------------------------------------------------------
__global__ __launch_bounds__(256) void attn_kernel(
    const u16* __restrict__ Q, const u16* __restrict__ Kp,
    const u16* __restrict__ Vp, u16* __restrict__ O)
{
    __shared__ u16 Ks[64][72];      // [key][d], pad 64->72
    __shared__ u16 Vt[64][72];      // [d][key]
    __shared__ u16 Ps[4][16][72];   // per-wave P: [q][key]
    const int tid = threadIdx.x, lane = tid & 63, wave = tid >> 6;
    const int lrow = lane & 15, quad = lane >> 4, kq = quad << 3;
    const int bh = blockIdx.y;
    const long base = (long)bh * 2048 * 64;
    const int q0 = blockIdx.x << 6;
    const int qrow = q0 + (wave << 4) + lrow;

    const bf16x8 aq0 = *(const bf16x8*)(Q + base + (long)qrow * 64 + kq);
    const bf16x8 aq1 = *(const bf16x8*)(Q + base + (long)qrow * 64 + 32 + kq);

    floatx4 oacc[4];
    #pragma unroll
    for (int i = 0; i < 4; ++i) oacc[i] = floatx4{0.f, 0.f, 0.f, 0.f};
    float mrun[4] = {-1e30f, -1e30f, -1e30f, -1e30f};
    float lrun[4] = {0.f, 0.f, 0.f, 0.f};

    for (int kv0 = 0; kv0 < 2048; kv0 += 64) {
        __syncthreads();
        #pragma unroll
        for (int it = 0; it < 2; ++it) {
            const int l = tid + it * 256;
            const int r = l >> 3, sg = (l & 7) << 3;
            *(uint4*)&Ks[r][sg] = *(const uint4*)(Kp + base + (long)(kv0 + r) * 64 + sg);
        }
        #pragma unroll
        for (int it = 0; it < 2; ++it) {
            const int l = tid + it * 256;
            const int key = l & 63, sg = (l >> 6) << 3;
            uint4 tmp = *(const uint4*)(Vp + base + (long)(kv0 + key) * 64 + sg);
            const u16* tp = (const u16*)&tmp;
            #pragma unroll
            for (int j = 0; j < 8; ++j) Vt[sg + j][key] = tp[j];
        }
        __syncthreads();

        floatx4 sc[4];
        #pragma unroll
        for (int ns = 0; ns < 4; ++ns) {
            const bf16x8 kf0 = *(const bf16x8*)&Ks[(ns << 4) + lrow][kq];
            const bf16x8 kf1 = *(const bf16x8*)&Ks[(ns << 4) + lrow][32 + kq];
            floatx4 c = floatx4{0.f, 0.f, 0.f, 0.f};
            c = __builtin_amdgcn_mfma_f32_16x16x32_bf16(aq0, kf0, c, 0, 0, 0);
            c = __builtin_amdgcn_mfma_f32_16x16x32_bf16(aq1, kf1, c, 0, 0, 0);
            sc[ns] = c * 0.125f;   // 1/sqrt(64)
        }

        #pragma unroll
        for (int r = 0; r < 4; ++r) {
            float mt = fmaxf(fmaxf(sc[0][r], sc[1][r]), fmaxf(sc[2][r], sc[3][r]));
            mt = fmaxf(mt, __shfl_xor(mt, 1));
            mt = fmaxf(mt, __shfl_xor(mt, 2));
            mt = fmaxf(mt, __shfl_xor(mt, 4));
            mt = fmaxf(mt, __shfl_xor(mt, 8));
            const float mnew  = fmaxf(mrun[r], mt);
            const float alpha = __expf(mrun[r] - mnew);
            float rs = 0.f;
            #pragma unroll
            for (int ns = 0; ns < 4; ++ns) {
                const float p = __expf(sc[ns][r] - mnew);
                Ps[wave][(quad << 2) + r][(ns << 4) + lrow] = f2bf(p);
                rs += p;
            }
            rs += __shfl_xor(rs, 1);
            rs += __shfl_xor(rs, 2);
            rs += __shfl_xor(rs, 4);
            rs += __shfl_xor(rs, 8);
            lrun[r] = lrun[r] * alpha + rs;
            mrun[r] = mnew;
            #pragma unroll
            for (int ns = 0; ns < 4; ++ns) oacc[ns][r] *= alpha;
        }
        __syncthreads();   // Ps visible (uniform across waves)

        const bf16x8 pf0 = *(const bf16x8*)&Ps[wave][lrow][kq];
        const bf16x8 pf1 = *(const bf16x8*)&Ps[wave][lrow][32 + kq];
        #pragma unroll
        for (int ns = 0; ns < 4; ++ns) {
            const bf16x8 vf0 = *(const bf16x8*)&Vt[(ns << 4) + lrow][kq];
            const bf16x8 vf1 = *(const bf16x8*)&Vt[(ns << 4) + lrow][32 + kq];
            oacc[ns] = __builtin_amdgcn_mfma_f32_16x16x32_bf16(pf0, vf0, oacc[ns], 0, 0, 0);
            oacc[ns] = __builtin_amdgcn_mfma_f32_16x16x32_bf16(pf1, vf1, oacc[ns], 0, 0, 0);
        }
    }

    const int b = bh >> 4, h = bh & 15;
    #pragma unroll
    for (int ns = 0; ns < 4; ++ns) {
        #pragma unroll
        for (int r = 0; r < 4; ++r) {
            const int q = q0 + (wave << 4) + (quad << 2) + r;
            const long token = (long)b * 2048 + q;
            const int col = (h << 6) + (ns << 4) + lrow;
            O[token * 1024 + col] = f2bf(oacc[ns][r] / lrun[r]);
        }
    }
}

// ---------------------------------------------------------------------------
// Host launcher
// ---------------------------------------------------------------------------
extern "C" void kernel_launch(void* const* d_in, const int* in_sizes, int n_in,
                              void* d_out, int out_size, void* d_ws, size_t ws_size,
                              hipStream_t stream)
{
    const float* x     = (const float*)d_in[0];
    const float* ln1_g = (const float*)d_in[1];
    const float* ln1_b = (const float*)d_in[2];
    const float* wq    = (const float*)d_in[3];
    const float* bq    = (const float*)d_in[4];
    const float* wk    = (const float*)d_in[5];
    const float* bk    = (const float*)d_in[6];
    const float* wv    = (const float*)d_in[7];
    const float* bv    = (const float*)d_in[8];
    const float* wo    = (const float*)d_in[9];
    const float* bo    = (const float*)d_in[10];
    const float* w1    = (const float*)d_in[11];
    const float* b1    = (const float*)d_in[12];
    const float* w2    = (const float*)d_in[13];
    const float* b2    = (const float*)d_in[14];
    const float* ln2_g = (const float*)d_in[15];
    const float* ln2_b = (const float*)d_in[16];
    float* out = (float*)d_out;

    char* w = (char*)d_ws;
    const size_t MB = 1024 * 1024;
    u16*   wqt   = (u16*)(w + 0  * MB);   // 2 MB each
    u16*   wkt   = (u16*)(w + 2  * MB);
    u16*   wvt   = (u16*)(w + 4  * MB);
    u16*   wot   = (u16*)(w + 6  * MB);
    u16*   w1t   = (u16*)(w + 8  * MB);   // 8 MB
    u16*   w2t   = (u16*)(w + 16 * MB);   // 8 MB
    u16*   h1    = (u16*)(w + 24 * MB);   // 8 MB, reused as attnb
    u16*   qb    = (u16*)(w + 32 * MB);   // 8 MB, reused as h2
    u16*   kb    = (u16*)(w + 40 * MB);   // 8 MB
    u16*   vb    = (u16*)(w + 48 * MB);   // 8 MB
    float* x1    = (float*)(w + 56 * MB); // 16 MB
    u16*   ffb   = (u16*)(w + 72 * MB);   // 32 MB  -> 104 MB total
    u16*   attnb = h1;
    u16*   h2    = qb;

    const dim3 tb(32, 8);
    transpose_cvt<<<dim3(32, 32),  tb, 0, stream>>>(wq, wqt, 1024, 1024);
    transpose_cvt<<<dim3(32, 32),  tb, 0, stream>>>(wk, wkt, 1024, 1024);
    transpose_cvt<<<dim3(32, 32),  tb, 0, stream>>>(wv, wvt, 1024, 1024);
    transpose_cvt<<<dim3(32, 32),  tb, 0, stream>>>(wo, wot, 1024, 1024);
    transpose_cvt<<<dim3(128, 32), tb, 0, stream>>>(w1, w1t, 1024, 4096);
    transpose_cvt<<<dim3(32, 128), tb, 0, stream>>>(w2, w2t, 4096, 1024);

    ln_kernel<<<4096, 256, 0, stream>>>(x, ln1_g, ln1_b, h1);

    gemm_kernel<0><<<dim3(8, 32), 256, 0, stream>>>(h1, wqt, bq, nullptr, qb, 1024, 1024);
    gemm_kernel<0><<<dim3(8, 32), 256, 0, stream>>>(h1, wkt, bk, nullptr, kb, 1024, 1024);
    gemm_kernel<0><<<dim3(8, 32), 256, 0, stream>>>(h1, wvt, bv, nullptr, vb, 1024, 1024);

    attn_kernel<<<dim3(32, 32), 256, 0, stream>>>(qb, kb, vb, attnb);

    gemm_kernel<1><<<dim3(8, 32), 256, 0, stream>>>(attnb, wot, bo, x, x1, 1024, 1024);

    ln_kernel<<<4096, 256, 0, stream>>>(x1, ln2_g, ln2_b, h2);

    gemm_kernel<2><<<dim3(32, 32), 256, 0, stream>>>(h2, w1t, b1, nullptr, ffb, 1024, 4096);
    gemm_kernel<1><<<dim3(8, 32), 256, 0, stream>>>(ffb, w2t, b2, x1, out, 4096, 1024);
}